// Round 16
// baseline (33.484 us; speedup 1.0000x reference)
//
#include <hip/hip_runtime.h>

#define NPART 4096
#define DIM 32
#define LOG2E 1.44269504088896340736f
#define RSTR 72  // row stride in halves: 4 cells x 16 halves + 8 pad = 144 B

typedef _Float16 f16x8 __attribute__((ext_vector_type(8)));
typedef _Float16 f16x4 __attribute__((ext_vector_type(4)));
typedef float f32x4 __attribute__((ext_vector_type(4)));

// ---------------------------------------------------------------------------
// Single-pass kernel, 64-row i-tile: block = 64 i x 256 j, grid (64,16).
// Halves device-wide fp32->fp16 staging redundancy vs the 32-row tile.
// 4 double-buffered stages of 64 j-rows (R15 cell layout: [row][cell][hi8|lo8]).
// out pre-zeroed by memset node; atomic accumulate of linear contribution.
__global__ __launch_bounds__(256, 4) void svgd_onepass_kernel(
    const float* __restrict__ X, const float* __restrict__ ls,
    float* __restrict__ out) {
  // carve: hl0 9216 + m0 256 + hl1 9216 + m1 256 = 18944 | sT overlay 32768 | sS 1024
  __shared__ __align__(16) unsigned char smem[33792];
  _Float16* hl0 = (_Float16*)smem;
  float* m0 = (float*)(smem + 9216);
  _Float16* hl1 = (_Float16*)(smem + 9472);
  float* m1 = (float*)(smem + 18688);
  float* sT = (float*)smem;            // overlay [4][64][32] (after last barrier)
  float* sS = (float*)(smem + 32768);  // [4][64]

  const int tid = threadIdx.x;
  const int lane = tid & 63;
  const int g = lane >> 4;    // 0..3
  const int li = lane & 15;   // 0..15
  const int wave = tid >> 6;  // 0..3
  const int i0 = blockIdx.x * 64;
  const int jb0 = blockIdx.y * 256;

  const float lsv = ls[0];
  const float inv = 1.f / (lsv * lsv);
  const float si2 = LOG2E * inv;
  const float hm = 0.5f * si2;

  const float4* X4 = (const float4*)X;

  // ---- 4 i-subtile fragment sets + norms (verified R3 lane mapping) ----
  f16x8 bh0, bl0, bh1, bl1, bh2, bl2, bh3, bl3;
  float mi0, mi1, mi2, mi3;
  {
    auto LOADI = [&](int sub, f16x8& bh, f16x8& bl, float& mi) {
      const int r = i0 + sub * 16 + li;
      float4 a = X4[(size_t)r * 8 + g], b = X4[(size_t)r * 8 + 4 + g];
      float t[8] = {a.x, a.y, a.z, a.w, b.x, b.y, b.z, b.w};
      float n = 0.f;
#pragma unroll
      for (int e = 0; e < 8; ++e) {
        n = fmaf(t[e], t[e], n);
        _Float16 h = (_Float16)t[e];
        bh[e] = h;
        bl[e] = (_Float16)(t[e] - (float)h);
      }
      n += __shfl_xor(n, 16, 64);
      n += __shfl_xor(n, 32, 64);
      mi = n * hm;
    };
    LOADI(0, bh0, bl0, mi0);
    LOADI(1, bh1, bl1, mi1);
    LOADI(2, bh2, bl2, mi2);
    LOADI(3, bh3, bl3, mi3);
  }

  f32x4 c2a0 = {0.f, 0.f, 0.f, 0.f}, c2b0 = {0.f, 0.f, 0.f, 0.f};
  f32x4 c2a1 = {0.f, 0.f, 0.f, 0.f}, c2b1 = {0.f, 0.f, 0.f, 0.f};
  f32x4 c2a2 = {0.f, 0.f, 0.f, 0.f}, c2b2 = {0.f, 0.f, 0.f, 0.f};
  f32x4 c2a3 = {0.f, 0.f, 0.f, 0.f}, c2b3 = {0.f, 0.f, 0.f, 0.f};
  float Sp0 = 0.f, Sp1 = 0.f, Sp2 = 0.f, Sp3 = 0.f;

  const int r_st = tid >> 2, ss_st = tid & 3;  // staging row / cell

  auto STAGE = [&](int s, _Float16* hl, float* m2b) {
    const int row = jb0 + s * 64 + r_st;
    float4 a = X4[(size_t)row * 8 + ss_st];
    float4 b = X4[(size_t)row * 8 + 4 + ss_st];
    float tv[8] = {a.x, a.y, a.z, a.w, b.x, b.y, b.z, b.w};
    f16x8 hi, lo;
    float nrm = 0.f;
#pragma unroll
    for (int e = 0; e < 8; ++e) {
      nrm = fmaf(tv[e], tv[e], nrm);
      _Float16 hh = (_Float16)tv[e];
      hi[e] = hh;
      lo[e] = (_Float16)(tv[e] - (float)hh);
    }
    _Float16* cell = hl + r_st * RSTR + ss_st * 16;
    *(f16x8*)(cell) = hi;
    *(f16x8*)(cell + 8) = lo;
    nrm += __shfl_xor(nrm, 1, 64);
    nrm += __shfl_xor(nrm, 2, 64);
    if (ss_st == 0) m2b[r_st] = nrm * hm;
  };

  auto COMP = [&](const _Float16* hl, const float* m2b) {
    const int jloc = wave * 16;
    const _Float16* cell = hl + (jloc + li) * RSTR + g * 16;
    f16x8 Ah = *(const f16x8*)(cell);
    f16x8 Al = *(const f16x8*)(cell + 8);
    const _Float16* bb = hl + (jloc + 4 * g) * RSTR + (li >> 2) * 16 + (li & 3);
    f16x4 Ba, Bb;
#pragma unroll
    for (int e = 0; e < 4; ++e) {
      Ba[e] = bb[e * RSTR];      // d = li
      Bb[e] = bb[e * RSTR + 4];  // d = 16 + li
    }
    f32x4 Mj = *(const f32x4*)(m2b + jloc + 4 * g);

    auto SUBT = [&](const f16x8& bh, const f16x8& bl, float mi, float& Sp,
                    f32x4& c2a, f32x4& c2b) {
      f32x4 c1 = {0.f, 0.f, 0.f, 0.f};
      c1 = __builtin_amdgcn_mfma_f32_16x16x32_f16(Ah, bh, c1, 0, 0, 0);
      c1 = __builtin_amdgcn_mfma_f32_16x16x32_f16(Al, bh, c1, 0, 0, 0);
      c1 = __builtin_amdgcn_mfma_f32_16x16x32_f16(Ah, bl, c1, 0, 0, 0);
      f16x4 a2;
#pragma unroll
      for (int r = 0; r < 4; ++r) {
        float k = exp2f(fmaf(c1[r], si2, -(mi + Mj[r])));
        Sp += k;
        a2[r] = (_Float16)k;
      }
      c2a = __builtin_amdgcn_mfma_f32_16x16x16f16(a2, Ba, c2a, 0, 0, 0);
      c2b = __builtin_amdgcn_mfma_f32_16x16x16f16(a2, Bb, c2b, 0, 0, 0);
    };
    SUBT(bh0, bl0, mi0, Sp0, c2a0, c2b0);
    SUBT(bh1, bl1, mi1, Sp1, c2a1, c2b1);
    SUBT(bh2, bl2, mi2, Sp2, c2a2, c2b2);
    SUBT(bh3, bl3, mi3, Sp3, c2a3, c2b3);
  };

  STAGE(0, hl0, m0);
  __syncthreads();
#pragma unroll
  for (int s = 0; s < 4; ++s) {
    _Float16* curH = (s & 1) ? hl1 : hl0;
    float* curM = (s & 1) ? m1 : m0;
    if (s < 3) STAGE(s + 1, (s & 1) ? hl0 : hl1, (s & 1) ? m0 : m1);
    COMP(curH, curM);
    __syncthreads();  // next-stage writes visible; current reads complete
  }

  // per-wave partials -> LDS (sT overlay safe after last barrier above)
  {
    auto STORE = [&](int sub, const f32x4& c2a, const f32x4& c2b, float Sp,
                     float& dummy) {
#pragma unroll
      for (int r = 0; r < 4; ++r) {
        sT[((size_t)wave * 64 + sub * 16 + 4 * g + r) * 32 + li] = c2a[r];
        sT[((size_t)wave * 64 + sub * 16 + 4 * g + r) * 32 + 16 + li] = c2b[r];
      }
      float sv = Sp;
      sv += __shfl_xor(sv, 16, 64);
      sv += __shfl_xor(sv, 32, 64);
      if (g == 0) sS[wave * 64 + sub * 16 + li] = sv;
      (void)dummy;
    };
    float dummy = 0.f;
    STORE(0, c2a0, c2b0, Sp0, dummy);
    STORE(1, c2a1, c2b1, Sp1, dummy);
    STORE(2, c2a2, c2b2, Sp2, dummy);
    STORE(3, c2a3, c2b3, Sp3, dummy);
  }
  __syncthreads();

  const float c1f = inv * (1.f / NPART);
  const float c2f = (1.f + inv) * (1.f / NPART);
#pragma unroll
  for (int q = 0; q < 8; ++q) {
    const int v = q * 256 + tid;  // 0..2047 over 64 rows x 32 d
    const int row = v >> 5, d = v & 31;
    const float T = sT[(0 * 64 + row) * 32 + d] + sT[(1 * 64 + row) * 32 + d] +
                    sT[(2 * 64 + row) * 32 + d] + sT[(3 * 64 + row) * 32 + d];
    const float S = sS[0 * 64 + row] + sS[1 * 64 + row] + sS[2 * 64 + row] +
                    sS[3 * 64 + row];
    const size_t idx = (size_t)(i0 + row) * DIM + d;
    unsafeAtomicAdd(&out[idx], c1f * S * X[idx] - c2f * T);
  }
}

// ---------------------------------------------------------------------------
// Fallback (used only if memset capture fails): single pass fp32, LDS tiles,
// writes out directly — no zeroing needed.
#define TJ 64
__global__ __launch_bounds__(256) void svgd_direct_kernel(const float* __restrict__ X,
                                                          const float* __restrict__ ls,
                                                          float* __restrict__ out) {
  __shared__ float4 sX[TJ * 8];
  const int tid = threadIdx.x;
  const int row = blockIdx.x * 256 + tid;
  const float lsv = ls[0];
  const float ls2 = lsv * lsv;
  const float inv2 = 0.5f / ls2;
  float4 xi[8];
  const float4* xr = reinterpret_cast<const float4*>(X + (size_t)row * DIM);
#pragma unroll
  for (int q = 0; q < 8; ++q) xi[q] = xr[q];
  float4 acc[8];
#pragma unroll
  for (int q = 0; q < 8; ++q) acc[q] = make_float4(0.f, 0.f, 0.f, 0.f);
  float S = 0.f;
  for (int jb = 0; jb < NPART; jb += TJ) {
    __syncthreads();
    const float4* src = reinterpret_cast<const float4*>(X + (size_t)jb * DIM);
    for (int t = tid; t < TJ * 8; t += 256) sX[t] = src[t];
    __syncthreads();
    for (int t = 0; t < TJ; ++t) {
      const float4* xj = &sX[t * 8];
      float4 v[8];
      float d0 = 0.f, d1 = 0.f, d2 = 0.f, d3 = 0.f;
#pragma unroll
      for (int q = 0; q < 8; ++q) {
        v[q] = xj[q];
        float ax = xi[q].x - v[q].x; d0 = fmaf(ax, ax, d0);
        float ay = xi[q].y - v[q].y; d1 = fmaf(ay, ay, d1);
        float az = xi[q].z - v[q].z; d2 = fmaf(az, az, d2);
        float aw = xi[q].w - v[q].w; d3 = fmaf(aw, aw, d3);
      }
      float k = __expf(-((d0 + d1) + (d2 + d3)) * inv2);
      S += k;
#pragma unroll
      for (int q = 0; q < 8; ++q) {
        acc[q].x = fmaf(k, v[q].x, acc[q].x);
        acc[q].y = fmaf(k, v[q].y, acc[q].y);
        acc[q].z = fmaf(k, v[q].z, acc[q].z);
        acc[q].w = fmaf(k, v[q].w, acc[q].w);
      }
    }
  }
  const float inv = 1.f / ls2;
  const float c1 = inv * S;
  const float c2 = 1.f + inv;
  float4* o = reinterpret_cast<float4*>(out + (size_t)row * DIM);
#pragma unroll
  for (int q = 0; q < 8; ++q) {
    float4 r;
    r.x = (c1 * xi[q].x - c2 * acc[q].x) * (1.f / NPART);
    r.y = (c1 * xi[q].y - c2 * acc[q].y) * (1.f / NPART);
    r.z = (c1 * xi[q].z - c2 * acc[q].z) * (1.f / NPART);
    r.w = (c1 * xi[q].w - c2 * acc[q].w) * (1.f / NPART);
    o[q] = r;
  }
}

// ---------------------------------------------------------------------------
extern "C" void kernel_launch(void* const* d_in, const int* in_sizes, int n_in,
                              void* d_out, int out_size, void* d_ws, size_t ws_size,
                              hipStream_t stream) {
  const float* X = (const float*)d_in[0];
  const float* ls = (const float*)d_in[1];
  float* out = (float*)d_out;
  (void)d_ws;
  (void)ws_size;

  hipError_t e =
      hipMemsetAsync(d_out, 0, (size_t)out_size * sizeof(float), stream);
  if (e == hipSuccess) {
    dim3 grid(NPART / 64, 16);
    svgd_onepass_kernel<<<grid, 256, 0, stream>>>(X, ls, out);
    return;
  }
  svgd_direct_kernel<<<NPART / 256, 256, 0, stream>>>(X, ls, out);
}

// Round 17
// 25.572 us; speedup vs baseline: 1.3094x; 1.3094x over previous
//
#include <hip/hip_runtime.h>

#define NPART 4096
#define DIM 32
#define LOG2E 1.44269504088896340736f
#define SHSTR 36  // padded row stride (halves) for sHi/sLo (R13-verified)

typedef _Float16 f16x8 __attribute__((ext_vector_type(8)));
typedef _Float16 f16x4 __attribute__((ext_vector_type(4)));
typedef float f32x4 __attribute__((ext_vector_type(4)));

// ---------------------------------------------------------------------------
// Single-pass kernel, 8-blocks/CU variant (R14, session best: 25.72 us).
// 8 stages x 64 j-rows keeps LDS at 16.9 KB so 8 blocks co-reside per CU.
// out pre-zeroed by memset node; atomic accumulate of linear contribution.
__global__ __launch_bounds__(256, 4) void svgd_onepass_kernel(
    const float* __restrict__ X, const float* __restrict__ ls,
    float* __restrict__ out) {
  // LDS carve (16896 B). sT overlays staging buffers after the final barrier.
  __shared__ __align__(16) unsigned char smem[16896];
  _Float16* sHi = (_Float16*)smem;             // [64][SHSTR] frag-order hi
  _Float16* sLo = (_Float16*)(smem + 4608);    // [64][SHSTR] frag-order lo
  _Float16* sXT = (_Float16*)(smem + 9216);    // [32][72] transpose (padded)
  float* sM2 = (float*)(smem + 13824);         // [64] scaled norms
  float* sT = (float*)smem;                    // overlay [4][32][32] = 16384 B
  float* sS = (float*)(smem + 16384);          // [4][32] (outside overlay)

  const int tid = threadIdx.x;
  const int lane = tid & 63;
  const int g = lane >> 4;    // 0..3
  const int li = lane & 15;   // 0..15
  const int wave = tid >> 6;  // 0..3
  const int i0 = blockIdx.x * 32;
  const int jb0 = blockIdx.y * 512;

  const float lsv = ls[0];
  const float inv = 1.f / (lsv * lsv);
  const float si2 = LOG2E * inv;
  const float hm = 0.5f * si2;

  const float4* X4 = (const float4*)X;

  // ---- i-tile fragments + norms, in registers (verified R3 lane mapping) --
  f16x8 bh0, bl0, bh1, bl1;
  float mi0, mi1;
  {
    const int r0 = i0 + li, r1 = i0 + 16 + li;
    float4 a0 = X4[(size_t)r0 * 8 + g], b0 = X4[(size_t)r0 * 8 + 4 + g];
    float4 a1 = X4[(size_t)r1 * 8 + g], b1 = X4[(size_t)r1 * 8 + 4 + g];
    float t0[8] = {a0.x, a0.y, a0.z, a0.w, b0.x, b0.y, b0.z, b0.w};
    float t1[8] = {a1.x, a1.y, a1.z, a1.w, b1.x, b1.y, b1.z, b1.w};
    float n0 = 0.f, n1 = 0.f;
#pragma unroll
    for (int e = 0; e < 8; ++e) {
      n0 = fmaf(t0[e], t0[e], n0);
      n1 = fmaf(t1[e], t1[e], n1);
      _Float16 h0 = (_Float16)t0[e];
      _Float16 h1 = (_Float16)t1[e];
      bh0[e] = h0; bl0[e] = (_Float16)(t0[e] - (float)h0);
      bh1[e] = h1; bl1[e] = (_Float16)(t1[e] - (float)h1);
    }
    n0 += __shfl_xor(n0, 16, 64);
    n0 += __shfl_xor(n0, 32, 64);
    n1 += __shfl_xor(n1, 16, 64);
    n1 += __shfl_xor(n1, 32, 64);
    mi0 = n0 * hm;
    mi1 = n1 * hm;
  }

  f32x4 c2a0 = {0.f, 0.f, 0.f, 0.f}, c2b0 = {0.f, 0.f, 0.f, 0.f};
  f32x4 c2a1 = {0.f, 0.f, 0.f, 0.f}, c2b1 = {0.f, 0.f, 0.f, 0.f};
  float Sp0 = 0.f, Sp1 = 0.f;

  // ---- 8 stages of 64 j-rows: convert to LDS, then 1 COMP iter/wave ----
  for (int s = 0; s < 8; ++s) {
    __syncthreads();  // prior-stage consumers done
    {
      const int r = tid >> 2, ss = tid & 3;  // r: row-in-stage 0..63
      const int row = jb0 + s * 64 + r;
      float4 a = X4[(size_t)row * 8 + ss];
      float4 b = X4[(size_t)row * 8 + 4 + ss];
      float tv[8] = {a.x, a.y, a.z, a.w, b.x, b.y, b.z, b.w};
      _Float16 h[8];
      f16x4 pl0, pl1;
      float nrm = 0.f;
#pragma unroll
      for (int e = 0; e < 8; ++e) {
        nrm = fmaf(tv[e], tv[e], nrm);
        _Float16 hh = (_Float16)tv[e];
        h[e] = hh;
        _Float16 ll = (_Float16)(tv[e] - (float)hh);
        if (e < 4) pl0[e] = ll; else pl1[e - 4] = ll;
      }
      // fragment g == ss for this thread's 8 elems (d = 4ss+e / 16+4ss+e-4)
      f16x4 ph0 = {h[0], h[1], h[2], h[3]};
      f16x4 ph1 = {h[4], h[5], h[6], h[7]};
      *(f16x4*)(sHi + r * SHSTR + ss * 8) = ph0;
      *(f16x4*)(sHi + r * SHSTR + ss * 8 + 4) = ph1;
      *(f16x4*)(sLo + r * SHSTR + ss * 8) = pl0;
      *(f16x4*)(sLo + r * SHSTR + ss * 8 + 4) = pl1;
#pragma unroll
      for (int e = 0; e < 8; ++e) {
        const int d = (e < 4) ? (4 * ss + e) : (16 + 4 * ss + (e - 4));
        sXT[d * 72 + r] = h[e];
      }
      nrm += __shfl_xor(nrm, 1, 64);
      nrm += __shfl_xor(nrm, 2, 64);
      if (ss == 0) sM2[r] = nrm * hm;
    }
    __syncthreads();

    {
      const int jloc = wave * 16;
      const _Float16* hb = sHi + (jloc + li) * SHSTR + g * 8;
      const _Float16* lb = sLo + (jloc + li) * SHSTR + g * 8;
      f16x4 AhL = *(const f16x4*)(hb);
      f16x4 AhH = *(const f16x4*)(hb + 4);
      f16x4 AlL = *(const f16x4*)(lb);
      f16x4 AlH = *(const f16x4*)(lb + 4);
      f16x8 Ah = __builtin_shufflevector(AhL, AhH, 0, 1, 2, 3, 4, 5, 6, 7);
      f16x8 Al = __builtin_shufflevector(AlL, AlH, 0, 1, 2, 3, 4, 5, 6, 7);
      f16x4 Ba = *(const f16x4*)(sXT + li * 72 + jloc + 4 * g);
      f16x4 Bb = *(const f16x4*)(sXT + (16 + li) * 72 + jloc + 4 * g);
      f32x4 Mj = *(const f32x4*)(sM2 + jloc + 4 * g);

      f32x4 c10 = {0.f, 0.f, 0.f, 0.f}, c11 = {0.f, 0.f, 0.f, 0.f};
      c10 = __builtin_amdgcn_mfma_f32_16x16x32_f16(Ah, bh0, c10, 0, 0, 0);
      c11 = __builtin_amdgcn_mfma_f32_16x16x32_f16(Ah, bh1, c11, 0, 0, 0);
      c10 = __builtin_amdgcn_mfma_f32_16x16x32_f16(Al, bh0, c10, 0, 0, 0);
      c11 = __builtin_amdgcn_mfma_f32_16x16x32_f16(Al, bh1, c11, 0, 0, 0);
      c10 = __builtin_amdgcn_mfma_f32_16x16x32_f16(Ah, bl0, c10, 0, 0, 0);
      c11 = __builtin_amdgcn_mfma_f32_16x16x32_f16(Ah, bl1, c11, 0, 0, 0);
      f16x4 a20, a21;
#pragma unroll
      for (int r = 0; r < 4; ++r) {
        float k0 = exp2f(fmaf(c10[r], si2, -(mi0 + Mj[r])));
        float k1 = exp2f(fmaf(c11[r], si2, -(mi1 + Mj[r])));
        Sp0 += k0;
        Sp1 += k1;
        a20[r] = (_Float16)k0;
        a21[r] = (_Float16)k1;
      }
      c2a0 = __builtin_amdgcn_mfma_f32_16x16x16f16(a20, Ba, c2a0, 0, 0, 0);
      c2b0 = __builtin_amdgcn_mfma_f32_16x16x16f16(a20, Bb, c2b0, 0, 0, 0);
      c2a1 = __builtin_amdgcn_mfma_f32_16x16x16f16(a21, Ba, c2a1, 0, 0, 0);
      c2b1 = __builtin_amdgcn_mfma_f32_16x16x16f16(a21, Bb, c2b1, 0, 0, 0);
    }
  }

  __syncthreads();  // all LDS reads done; sT overlay now safe

#pragma unroll
  for (int r = 0; r < 4; ++r) {
    sT[(wave * 32 + 4 * g + r) * 32 + li] = c2a0[r];
    sT[(wave * 32 + 4 * g + r) * 32 + 16 + li] = c2b0[r];
    sT[(wave * 32 + 16 + 4 * g + r) * 32 + li] = c2a1[r];
    sT[(wave * 32 + 16 + 4 * g + r) * 32 + 16 + li] = c2b1[r];
  }
  {
    float s0 = Sp0, s1 = Sp1;
    s0 += __shfl_xor(s0, 16, 64);
    s0 += __shfl_xor(s0, 32, 64);
    s1 += __shfl_xor(s1, 16, 64);
    s1 += __shfl_xor(s1, 32, 64);
    if (g == 0) {
      sS[wave * 32 + li] = s0;
      sS[wave * 32 + 16 + li] = s1;
    }
  }
  __syncthreads();

  const float c1f = inv * (1.f / NPART);
  const float c2f = (1.f + inv) * (1.f / NPART);
#pragma unroll
  for (int q = 0; q < 4; ++q) {
    const int v = q * 256 + tid;
    const int row = v >> 5, d = v & 31;
    const float T = sT[(0 * 32 + row) * 32 + d] + sT[(1 * 32 + row) * 32 + d] +
                    sT[(2 * 32 + row) * 32 + d] + sT[(3 * 32 + row) * 32 + d];
    const float S = sS[0 * 32 + row] + sS[1 * 32 + row] + sS[2 * 32 + row] +
                    sS[3 * 32 + row];
    const size_t idx = (size_t)(i0 + row) * DIM + d;
    unsafeAtomicAdd(&out[idx], c1f * S * X[idx] - c2f * T);
  }
}

// ---------------------------------------------------------------------------
// Fallback (used only if memset capture fails): single pass fp32, LDS tiles,
// writes out directly — no zeroing needed.
#define TJ 64
__global__ __launch_bounds__(256) void svgd_direct_kernel(const float* __restrict__ X,
                                                          const float* __restrict__ ls,
                                                          float* __restrict__ out) {
  __shared__ float4 sX[TJ * 8];
  const int tid = threadIdx.x;
  const int row = blockIdx.x * 256 + tid;
  const float lsv = ls[0];
  const float ls2 = lsv * lsv;
  const float inv2 = 0.5f / ls2;
  float4 xi[8];
  const float4* xr = reinterpret_cast<const float4*>(X + (size_t)row * DIM);
#pragma unroll
  for (int q = 0; q < 8; ++q) xi[q] = xr[q];
  float4 acc[8];
#pragma unroll
  for (int q = 0; q < 8; ++q) acc[q] = make_float4(0.f, 0.f, 0.f, 0.f);
  float S = 0.f;
  for (int jb = 0; jb < NPART; jb += TJ) {
    __syncthreads();
    const float4* src = reinterpret_cast<const float4*>(X + (size_t)jb * DIM);
    for (int t = tid; t < TJ * 8; t += 256) sX[t] = src[t];
    __syncthreads();
    for (int t = 0; t < TJ; ++t) {
      const float4* xj = &sX[t * 8];
      float4 v[8];
      float d0 = 0.f, d1 = 0.f, d2 = 0.f, d3 = 0.f;
#pragma unroll
      for (int q = 0; q < 8; ++q) {
        v[q] = xj[q];
        float ax = xi[q].x - v[q].x; d0 = fmaf(ax, ax, d0);
        float ay = xi[q].y - v[q].y; d1 = fmaf(ay, ay, d1);
        float az = xi[q].z - v[q].z; d2 = fmaf(az, az, d2);
        float aw = xi[q].w - v[q].w; d3 = fmaf(aw, aw, d3);
      }
      float k = __expf(-((d0 + d1) + (d2 + d3)) * inv2);
      S += k;
#pragma unroll
      for (int q = 0; q < 8; ++q) {
        acc[q].x = fmaf(k, v[q].x, acc[q].x);
        acc[q].y = fmaf(k, v[q].y, acc[q].y);
        acc[q].z = fmaf(k, v[q].z, acc[q].z);
        acc[q].w = fmaf(k, v[q].w, acc[q].w);
      }
    }
  }
  const float inv = 1.f / ls2;
  const float c1 = inv * S;
  const float c2 = 1.f + inv;
  float4* o = reinterpret_cast<float4*>(out + (size_t)row * DIM);
#pragma unroll
  for (int q = 0; q < 8; ++q) {
    float4 r;
    r.x = (c1 * xi[q].x - c2 * acc[q].x) * (1.f / NPART);
    r.y = (c1 * xi[q].y - c2 * acc[q].y) * (1.f / NPART);
    r.z = (c1 * xi[q].z - c2 * acc[q].z) * (1.f / NPART);
    r.w = (c1 * xi[q].w - c2 * acc[q].w) * (1.f / NPART);
    o[q] = r;
  }
}

// ---------------------------------------------------------------------------
extern "C" void kernel_launch(void* const* d_in, const int* in_sizes, int n_in,
                              void* d_out, int out_size, void* d_ws, size_t ws_size,
                              hipStream_t stream) {
  const float* X = (const float*)d_in[0];
  const float* ls = (const float*)d_in[1];
  float* out = (float*)d_out;
  (void)d_ws;
  (void)ws_size;

  hipError_t e =
      hipMemsetAsync(d_out, 0, (size_t)out_size * sizeof(float), stream);
  if (e == hipSuccess) {
    dim3 grid(NPART / 32, 8);
    svgd_onepass_kernel<<<grid, 256, 0, stream>>>(X, ls, out);
    return;
  }
  svgd_direct_kernel<<<NPART / 256, 256, 0, stream>>>(X, ls, out);
}